// Round 7
// baseline (100.222 us; speedup 1.0000x reference)
//
#include <hip/hip_runtime.h>
#include <math.h>

// Rational-quadratic spline, K=8 bins, tail B=3.
// R7: wave-autonomous double-buffered pipeline, ZERO barriers in the loop.
//     Each wave owns a private 2x6656B LDS slice and streams 21-22
//     contiguous 64-row tiles: issue next tile's 8 DMA ops -> counted
//     s_waitcnt vmcnt(8) (per-wave counter; no cross-wave coupling) ->
//     compute current. Every wave keeps ~6.6KB permanently in flight ->
//     ~79KB/CU outstanding (vs ~20KB for R5's block-level pipeline and
//     ~50% duty cycle for R4's load/compute lockstep), covering the
//     BW*latency product (~23KB) with margin.

#define TAILB 3.0f
#define MINSZ 0.001f
#define NBLK 768              // 3 blocks/CU * 256 CUs, fully resident
#define NWAVES 3072           // NBLK * 4
#define NTILES 65536          // 4194304 / 64
#define NFAT 1024             // first 1024 waves take 22 tiles, rest 21

typedef unsigned int u32;

__device__ __forceinline__ void gload_lds16(const void* g, void* l) {
    __builtin_amdgcn_global_load_lds(
        (const __attribute__((address_space(1))) u32*)g,
        (__attribute__((address_space(3))) u32*)l,
        16, 0, 0);
}

__device__ __forceinline__ float frcp(float x) {
    return __builtin_amdgcn_rcpf(x);   // v_rcp_f32, ~1 ulp
}

__device__ __forceinline__ float softplus_d(float u) {
    return fmaxf(u, 0.0f) + __logf(1.0f + __expf(-fabsf(u))) + MINSZ;
}

// Stage one 64-row tile (6400B params + 256B x) into this wave's buffer.
// Exactly 8 vm-ops per wave: 6 full-wave + 2 sixteen-lane masked DMAs.
// LDS dest is linear base + lane*16 (global_load_lds contract).
__device__ __forceinline__ void stage(const float4* __restrict__ p4g,
                                      const float4* __restrict__ x4g,
                                      float* buf, int tile, int lane)
{
    const float4* ps = p4g + (size_t)tile * 400;   // 64 rows * 25 floats
    float4* bd = (float4*)buf;
    #pragma unroll
    for (int v = 0; v < 6; ++v)
        gload_lds16(ps + v * 64 + lane, bd + v * 64 + lane);
    if (lane < 16) {
        gload_lds16(ps + 384 + lane, bd + 384 + lane);            // params tail
        gload_lds16(x4g + (size_t)tile * 16 + lane, bd + 400 + lane); // x block
    }
}

__launch_bounds__(256, 3)
__global__ void rqs_kernel(const float* __restrict__ x_in,
                           const float* __restrict__ params,
                           float* __restrict__ out,
                           float* __restrict__ partial)
{
    // per-wave private slices: [wave][dbuf][1664 floats] = 53248 B total
    __shared__ __align__(16) float lds[4][2][1664];
    __shared__ float wsum[4];

    const int tid  = threadIdx.x;
    const int wid  = tid >> 6;
    const int lane = tid & 63;
    const int gw   = blockIdx.x * 4 + wid;

    // contiguous tile chunks: first NFAT waves 22 tiles, rest 21
    const int nt = (gw < NFAT) ? 22 : 21;
    const int t0 = (gw < NFAT) ? gw * 22 : NFAT * 22 + (gw - NFAT) * 21;

    const float4* p4g = (const float4*)params;
    const float4* x4g = (const float4*)x_in;
    float* bufA = &lds[wid][0][0];
    float* bufB = &lds[wid][1][0];

    const float fac_num = (2.0f * TAILB) * (2.0f * TAILB - 8.0f * MINSZ); // 35.952
    float accv = 0.0f;

    stage(p4g, x4g, bufA, t0, lane);        // prologue: 8 ops in flight

    for (int k = 0; k < nt; ++k) {
        const int t = t0 + k;
        float* cur = (k & 1) ? bufB : bufA;
        float* nxt = (k & 1) ? bufA : bufB;

        if (k + 1 < nt) {
            stage(p4g, x4g, nxt, t + 1, lane);   // 8 more in flight
            // drain current tile's 8 (+ prior store); next 8 stay in flight
            asm volatile("s_waitcnt vmcnt(8)" ::: "memory");
        } else {
            // nothing new issued; allow the previous store to remain
            asm volatile("s_waitcnt vmcnt(1)" ::: "memory");
        }

        const float* row = cur + lane * 25;
        const float x = cur[1600 + lane];
        const float xi = fminf(fmaxf(x, -TAILB), TAILB);

        // ---- widths: softmax (no max-sub; N(0,1) inputs, fp32-safe) ----
        float ew[8];
        float s = 0.0f;
        #pragma unroll
        for (int j = 0; j < 8; ++j) { ew[j] = __expf(row[j]); s += ew[j]; }
        const float facw = fac_num * frcp(s);

        // fused cumsum + count + knot select (inner knots are monotone)
        float c = 0.0f;
        int idx = 0;
        float cw_k = -TAILB, cw_k1 = TAILB;
        bool found = false;
        #pragma unroll
        for (int j = 0; j < 7; ++j) {
            c = fmaf(ew[j], facw, c + MINSZ);
            const bool ge = (xi >= c);
            idx += ge ? 1 : 0;
            cw_k  = ge ? c : cw_k;
            cw_k1 = (!ge && !found) ? c : cw_k1;
            found = found || !ge;
        }

        // ---- heights: softmax + select by idx ----
        float ch_k = -TAILB, ch_k1 = TAILB;
        {
            float eh[8];
            float sh = 0.0f;
            #pragma unroll
            for (int j = 0; j < 8; ++j) { eh[j] = __expf(row[8 + j]); sh += eh[j]; }
            const float fach = fac_num * frcp(sh);
            c = 0.0f;
            #pragma unroll
            for (int j = 1; j <= 7; ++j) {
                c = fmaf(eh[j - 1], fach, c + MINSZ);
                ch_k  = (idx == j)     ? c : ch_k;
                ch_k1 = (idx + 1 == j) ? c : ch_k1;
            }
        }

        // ---- derivatives: exactly the 2 needed ----
        const float d_k  = softplus_d(row[16 + idx]);
        const float d_k1 = softplus_d(row[17 + idx]);

        // ---- rational-quadratic transform ----
        const float bw  = cw_k1 - cw_k;
        const float bh  = ch_k1 - ch_k;
        const float rbw = frcp(bw);
        const float th  = (xi - cw_k) * rbw;
        const float omt = 1.0f - th;
        const float th2 = th * th;
        const float t1m = th * omt;
        const float num = bh * fmaf(d_k, th2, d_k1 * t1m);
        const float den = fmaf(2.0f * d_k1, t1m, fmaf(d_k, th2, omt * omt));
        const float out_in = fmaf(num, frcp(den), ch_k);

        const bool inside = (x >= -TAILB) && (x <= TAILB);
        __builtin_nontemporal_store(inside ? out_in : x,
                                    &out[(size_t)t * 64 + lane]);

        // single merged v_log_f32
        float ldarg = d_k1 * d_k * bh * rbw;
        if (!__all(inside)) {
            const float d0 = softplus_d(row[16]);
            ldarg = inside ? ldarg : d0;
        }
        accv += __logf(ldarg);
    }

    // ---- wave reduce, then one block combine (the only sync) ----
    float acc = accv;
    #pragma unroll
    for (int off = 32; off > 0; off >>= 1)
        acc += __shfl_down(acc, off);
    if (lane == 0) wsum[wid] = acc;
    __syncthreads();
    if (tid == 0)
        partial[blockIdx.x] = (wsum[0] + wsum[1]) + (wsum[2] + wsum[3]);
}

__global__ void rqs_reduce(const float* __restrict__ partial, int nb,
                           float* __restrict__ out_sum)
{
    const int tid = threadIdx.x;              // 256 threads
    double acc = 0.0;
    for (int q = tid; q < nb; q += 256)
        acc += (double)partial[q];
    #pragma unroll
    for (int off = 32; off > 0; off >>= 1)
        acc += __shfl_down(acc, off);
    __shared__ double dsum[4];
    const int wave = tid >> 6, lane = tid & 63;
    if (lane == 0) dsum[wave] = acc;
    __syncthreads();
    if (tid == 0)
        *out_sum = (float)((dsum[0] + dsum[1]) + (dsum[2] + dsum[3]));
}

extern "C" void kernel_launch(void* const* d_in, const int* in_sizes, int n_in,
                              void* d_out, int out_size, void* d_ws, size_t ws_size,
                              hipStream_t stream) {
    const float* x      = (const float*)d_in[0];
    const float* params = (const float*)d_in[1];
    float* out = (float*)d_out;
    const int n = in_sizes[0];          // 4194304
    float* partial = (float*)d_ws;      // NBLK floats

    hipLaunchKernelGGL(rqs_kernel, dim3(NBLK), dim3(256), 0, stream,
                       x, params, out, partial);
    hipLaunchKernelGGL(rqs_reduce, dim3(1), dim3(256), 0, stream,
                       partial, NBLK, out + n);
}

// Round 8
// 87.541 us; speedup vs baseline: 1.1449x; 1.1449x over previous
//
#include <hip/hip_runtime.h>
#include <math.h>

// Rational-quadratic spline, K=8 bins, tail B=3.
// R8: R4 structure minus cross-wave coupling. Each wave DMAs its OWN 64 rows
//     (7 global_load_lds, 6.4KB) into its private LDS slice, waits its own
//     s_waitcnt vmcnt(0) -- NO s_barrier -- and computes immediately. Same
//     occupancy (6 blocks/CU, 24 waves), same conflict-free 100B-row layout,
//     x direct-loaded. Isolates "block-wide drain+barrier lockstep" as the
//     last candidate for the 15-20% gap to the streaming ceiling.

#define TAILB 3.0f
#define MINSZ 0.001f

typedef unsigned int u32;

__device__ __forceinline__ void gload_lds16(const void* g, void* l) {
    __builtin_amdgcn_global_load_lds(
        (const __attribute__((address_space(1))) u32*)g,
        (__attribute__((address_space(3))) u32*)l,
        16, 0, 0);
}

__device__ __forceinline__ float frcp(float x) {
    return __builtin_amdgcn_rcpf(x);   // v_rcp_f32, ~1 ulp
}

__device__ __forceinline__ float softplus_d(float u) {
    return fmaxf(u, 0.0f) + __logf(1.0f + __expf(-fabsf(u))) + MINSZ;
}

__launch_bounds__(256, 6)
__global__ void rqs_kernel(const float* __restrict__ x_in,
                           const float* __restrict__ params,
                           float* __restrict__ out,
                           float* __restrict__ partial)
{
    // per-wave private 64-row slices, packed 25-float rows (odd word stride
    // -> conflict-free ds_read_b32)
    __shared__ __align__(16) float lds[4][1600];
    __shared__ float wsum[4];

    const int tid  = threadIdx.x;
    const int wid  = tid >> 6;
    const int lane = tid & 63;
    const int bid  = blockIdx.x;
    const int i    = bid * 256 + tid;

    // ---- this wave stages its own 64 rows: 400 float4 chunks, 7 DMA ops ----
    const float4* ps = (const float4*)params + (size_t)bid * 1600 + wid * 400;
    float4* bd = (float4*)&lds[wid][0];
    #pragma unroll
    for (int v = 0; v < 6; ++v)
        gload_lds16(ps + v * 64 + lane, bd + v * 64 + lane);
    if (lane < 16)
        gload_lds16(ps + 384 + lane, bd + 384 + lane);

    const float x = x_in[i];                 // direct coalesced load

    // wait ONLY this wave's DMAs (+ x). No barrier: waves are independent.
    asm volatile("s_waitcnt vmcnt(0)" ::: "memory");

    const float* row = &lds[wid][lane * 25];
    const float xi = fminf(fmaxf(x, -TAILB), TAILB);
    const float fac_num = (2.0f * TAILB) * (2.0f * TAILB - 8.0f * MINSZ); // 35.952

    // ---- widths: softmax (no max-sub; N(0,1) inputs, fp32-safe) ----
    float ew[8];
    float s = 0.0f;
    #pragma unroll
    for (int j = 0; j < 8; ++j) { ew[j] = __expf(row[j]); s += ew[j]; }
    const float facw = fac_num * frcp(s);

    // fused cumsum + count + knot select (inner knots are monotone)
    float c = 0.0f;
    int idx = 0;
    float cw_k = -TAILB, cw_k1 = TAILB;
    bool found = false;
    #pragma unroll
    for (int j = 0; j < 7; ++j) {
        c = fmaf(ew[j], facw, c + MINSZ);
        const bool ge = (xi >= c);
        idx += ge ? 1 : 0;
        cw_k  = ge ? c : cw_k;
        cw_k1 = (!ge && !found) ? c : cw_k1;
        found = found || !ge;
    }

    // ---- heights: softmax + select by idx ----
    float ch_k = -TAILB, ch_k1 = TAILB;
    {
        float eh[8];
        float sh = 0.0f;
        #pragma unroll
        for (int j = 0; j < 8; ++j) { eh[j] = __expf(row[8 + j]); sh += eh[j]; }
        const float fach = fac_num * frcp(sh);
        c = 0.0f;
        #pragma unroll
        for (int j = 1; j <= 7; ++j) {
            c = fmaf(eh[j - 1], fach, c + MINSZ);
            ch_k  = (idx == j)     ? c : ch_k;
            ch_k1 = (idx + 1 == j) ? c : ch_k1;
        }
    }

    // ---- derivatives: exactly the 2 needed (idx==0 makes d_k == d0) ----
    const float d_k  = softplus_d(row[16 + idx]);
    const float d_k1 = softplus_d(row[17 + idx]);

    // ---- rational-quadratic transform ----
    const float bw  = cw_k1 - cw_k;
    const float bh  = ch_k1 - ch_k;
    const float rbw = frcp(bw);
    const float th  = (xi - cw_k) * rbw;
    const float omt = 1.0f - th;
    const float th2 = th * th;
    const float t1m = th * omt;
    const float num = bh * fmaf(d_k, th2, d_k1 * t1m);
    const float den = fmaf(2.0f * d_k1, t1m, fmaf(d_k, th2, omt * omt));
    const float out_in = fmaf(num, frcp(den), ch_k);

    const bool inside = (x >= -TAILB) && (x <= TAILB);
    out[i] = inside ? out_in : x;

    // merged single v_log_f32
    float ldarg = d_k1 * d_k * bh * rbw;
    if (!__all(inside)) {                 // only waves containing a tail lane
        const float d0 = softplus_d(row[16]);
        ldarg = inside ? ldarg : d0;
    }
    const float ldv = __logf(ldarg);

    // ---- wave reduce; single block combine (the only sync point) ----
    float acc = ldv;
    #pragma unroll
    for (int off = 32; off > 0; off >>= 1)
        acc += __shfl_down(acc, off);
    if (lane == 0) wsum[wid] = acc;
    __syncthreads();
    if (tid == 0)
        partial[bid] = (wsum[0] + wsum[1]) + (wsum[2] + wsum[3]);
}

__global__ void rqs_reduce(const float* __restrict__ partial, int nb,
                           float* __restrict__ out_sum)
{
    const int tid = threadIdx.x;              // 1024 threads
    const int nb4 = nb >> 2;                  // nb divisible by 4
    const float4* p4 = (const float4*)partial;
    double acc = 0.0;
    for (int q = tid; q < nb4; q += 1024) {
        float4 v = p4[q];
        acc += (double)v.x + (double)v.y + (double)v.z + (double)v.w;
    }
    #pragma unroll
    for (int off = 32; off > 0; off >>= 1)
        acc += __shfl_down(acc, off);
    __shared__ double wsum[16];
    const int wave = tid >> 6, lane = tid & 63;
    if (lane == 0) wsum[wave] = acc;
    __syncthreads();
    if (tid == 0) {
        double t = 0.0;
        #pragma unroll
        for (int w = 0; w < 16; ++w) t += wsum[w];
        *out_sum = (float)t;
    }
}

extern "C" void kernel_launch(void* const* d_in, const int* in_sizes, int n_in,
                              void* d_out, int out_size, void* d_ws, size_t ws_size,
                              hipStream_t stream) {
    const float* x      = (const float*)d_in[0];
    const float* params = (const float*)d_in[1];
    float* out = (float*)d_out;
    const int n = in_sizes[0];          // 4194304, divisible by 256
    const int nb = n / 256;             // 16384 blocks
    float* partial = (float*)d_ws;      // nb*4 = 64 KB scratch

    hipLaunchKernelGGL(rqs_kernel, dim3(nb), dim3(256), 0, stream,
                       x, params, out, partial);
    hipLaunchKernelGGL(rqs_reduce, dim3(1), dim3(1024), 0, stream,
                       partial, nb, out + n);
}

// Round 9
// 85.112 us; speedup vs baseline: 1.1775x; 1.0285x over previous
//
#include <hip/hip_runtime.h>
#include <math.h>

// Rational-quadratic spline, K=8 bins, tail B=3.
// R9: exact R4 structure (best, 87.3us) + two address-stream tweaks:
//     (1) bijective XCD swizzle: block (bid&7)*2048 + (bid>>3) gives each
//         XCD one contiguous ~52MB slab -> linear L2-miss sweeps, better
//         DRAM page locality (default round-robin hops 204.8KB per block).
//     (2) nontemporal out/partial stores + nontemporal x load: single-use
//         traffic stays out of the Infinity Cache, preserving the ~50%
//         params retention seen in FETCH_SIZE (213MB vs 417MB demand).

#define TAILB 3.0f
#define MINSZ 0.001f

typedef unsigned int u32;

__device__ __forceinline__ void gload_lds16(const void* g, void* l) {
    __builtin_amdgcn_global_load_lds(
        (const __attribute__((address_space(1))) u32*)g,
        (__attribute__((address_space(3))) u32*)l,
        16, 0, 0);
}

__device__ __forceinline__ float frcp(float x) {
    return __builtin_amdgcn_rcpf(x);   // v_rcp_f32, ~1 ulp
}

__device__ __forceinline__ float softplus_d(float u) {
    return fmaxf(u, 0.0f) + __logf(1.0f + __expf(-fabsf(u))) + MINSZ;
}

__launch_bounds__(256, 6)
__global__ void rqs_kernel(const float* __restrict__ x_in,
                           const float* __restrict__ params,
                           float* __restrict__ out,
                           float* __restrict__ partial)
{
    __shared__ __align__(16) float lds[256 * 25];
    __shared__ float wsum[4];

    const int tid = threadIdx.x;
    // bijective XCD swizzle: 16384 blocks, 8 XCDs, 2048 contiguous per XCD
    const int bid = (blockIdx.x & 7) * 2048 + (blockIdx.x >> 3);
    const int i = bid * 256 + tid;

    const float x = __builtin_nontemporal_load(&x_in[i]);

    // ---- stage 256 rows x 25 floats (25600 B) global->LDS, linear ----
    const float4* src = (const float4*)params + (size_t)bid * 1600;
    float4* dst = (float4*)lds;
    #pragma unroll
    for (int v = 0; v < 6; ++v) {
        const int q = tid + v * 256;
        gload_lds16(src + q, dst + q);
    }
    if (tid < 64) {
        const int q = tid + 1536;
        gload_lds16(src + q, dst + q);
    }

    const float xi = fminf(fmaxf(x, -TAILB), TAILB);
    __syncthreads();

    const float* row = &lds[tid * 25];
    const float fac_num = (2.0f * TAILB) * (2.0f * TAILB - 8.0f * MINSZ); // 35.952

    // ---- widths: softmax (no max-sub; N(0,1) inputs, fp32-safe) ----
    float ew[8];
    float s = 0.0f;
    #pragma unroll
    for (int j = 0; j < 8; ++j) { ew[j] = __expf(row[j]); s += ew[j]; }
    const float facw = fac_num * frcp(s);

    // fused cumsum + count + knot select (inner knots are monotone)
    float c = 0.0f;
    int idx = 0;
    float cw_k = -TAILB, cw_k1 = TAILB;
    bool found = false;
    #pragma unroll
    for (int j = 0; j < 7; ++j) {
        c = fmaf(ew[j], facw, c + MINSZ);
        const bool ge = (xi >= c);
        idx += ge ? 1 : 0;
        cw_k  = ge ? c : cw_k;
        cw_k1 = (!ge && !found) ? c : cw_k1;
        found = found || !ge;
    }

    // ---- heights: softmax + select by idx ----
    float ch_k = -TAILB, ch_k1 = TAILB;
    {
        float eh[8];
        float sh = 0.0f;
        #pragma unroll
        for (int j = 0; j < 8; ++j) { eh[j] = __expf(row[8 + j]); sh += eh[j]; }
        const float fach = fac_num * frcp(sh);
        c = 0.0f;
        #pragma unroll
        for (int j = 1; j <= 7; ++j) {
            c = fmaf(eh[j - 1], fach, c + MINSZ);
            ch_k  = (idx == j)     ? c : ch_k;
            ch_k1 = (idx + 1 == j) ? c : ch_k1;
        }
    }

    // ---- derivatives: exactly the 2 needed (idx==0 makes d_k == d0) ----
    const float d_k  = softplus_d(row[16 + idx]);
    const float d_k1 = softplus_d(row[17 + idx]);

    // ---- rational-quadratic transform ----
    const float bw  = cw_k1 - cw_k;
    const float bh  = ch_k1 - ch_k;
    const float rbw = frcp(bw);
    const float th  = (xi - cw_k) * rbw;
    const float omt = 1.0f - th;
    const float th2 = th * th;
    const float t1m = th * omt;
    const float num = bh * fmaf(d_k, th2, d_k1 * t1m);
    const float den = fmaf(2.0f * d_k1, t1m, fmaf(d_k, th2, omt * omt));
    const float out_in = fmaf(num, frcp(den), ch_k);

    const bool inside = (x >= -TAILB) && (x <= TAILB);
    __builtin_nontemporal_store(inside ? out_in : x, &out[i]);

    // log(dk1*dk*bh/bw); merged with outside branch's log(d0): ONE v_log_f32
    float ldarg = d_k1 * d_k * bh * rbw;
    if (!__all(inside)) {                 // only waves containing a tail lane
        const float d0 = softplus_d(row[16]);
        ldarg = inside ? ldarg : d0;
    }
    const float ldv = __logf(ldarg);

    // ---- block reduction (float tree; error << threshold) ----
    float acc = ldv;
    #pragma unroll
    for (int off = 32; off > 0; off >>= 1)
        acc += __shfl_down(acc, off);
    const int wave = tid >> 6, lane = tid & 63;
    if (lane == 0) wsum[wave] = acc;
    __syncthreads();
    if (tid == 0)
        __builtin_nontemporal_store((wsum[0] + wsum[1]) + (wsum[2] + wsum[3]),
                                    &partial[bid]);
}

__global__ void rqs_reduce(const float* __restrict__ partial, int nb,
                           float* __restrict__ out_sum)
{
    const int tid = threadIdx.x;              // 1024 threads
    const int nb4 = nb >> 2;                  // nb divisible by 4
    const float4* p4 = (const float4*)partial;
    double acc = 0.0;
    for (int q = tid; q < nb4; q += 1024) {
        float4 v = p4[q];
        acc += (double)v.x + (double)v.y + (double)v.z + (double)v.w;
    }
    #pragma unroll
    for (int off = 32; off > 0; off >>= 1)
        acc += __shfl_down(acc, off);
    __shared__ double wsum[16];
    const int wave = tid >> 6, lane = tid & 63;
    if (lane == 0) wsum[wave] = acc;
    __syncthreads();
    if (tid == 0) {
        double t = 0.0;
        #pragma unroll
        for (int w = 0; w < 16; ++w) t += wsum[w];
        *out_sum = (float)t;
    }
}

extern "C" void kernel_launch(void* const* d_in, const int* in_sizes, int n_in,
                              void* d_out, int out_size, void* d_ws, size_t ws_size,
                              hipStream_t stream) {
    const float* x      = (const float*)d_in[0];
    const float* params = (const float*)d_in[1];
    float* out = (float*)d_out;
    const int n = in_sizes[0];          // 4194304, divisible by 256
    const int nb = n / 256;             // 16384 blocks (divisible by 8)
    float* partial = (float*)d_ws;      // nb*4 = 64 KB scratch

    hipLaunchKernelGGL(rqs_kernel, dim3(nb), dim3(256), 0, stream,
                       x, params, out, partial);
    hipLaunchKernelGGL(rqs_reduce, dim3(1), dim3(1024), 0, stream,
                       partial, nb, out + n);
}

// Round 10
// 84.848 us; speedup vs baseline: 1.1812x; 1.0031x over previous
//
#include <hip/hip_runtime.h>
#include <math.h>

// Rational-quadratic spline, K=8 bins, tail B=3.
// R10: R9 (best, 85.1us: XCD swizzle + nt out/x) with ONE variable changed:
//      staging mechanism. global_load_lds DMA -> plain VGPR loads
//      (global_load_dwordx4) + ds_write_b128. Rationale: all DMA-staged
//      variants plateau at 5.2-5.3 TB/s while VGPR-path streams (m13 copy,
//      harness fills) demonstrate 6.3-6.9 TB/s on this chip -- testing
//      whether the LDS-DMA engine caps below the VMEM-return path.
//      Per-wave private slices (wave-in-order LDS => no block barrier,
//      one lgkmcnt fence). VGPR ~70 < 85 cap for 6 blocks/CU (24 waves).

#define TAILB 3.0f
#define MINSZ 0.001f

__device__ __forceinline__ float frcp(float x) {
    return __builtin_amdgcn_rcpf(x);   // v_rcp_f32, ~1 ulp
}

__device__ __forceinline__ float softplus_d(float u) {
    return fmaxf(u, 0.0f) + __logf(1.0f + __expf(-fabsf(u))) + MINSZ;
}

__launch_bounds__(256, 6)
__global__ void rqs_kernel(const float* __restrict__ x_in,
                           const float* __restrict__ params,
                           float* __restrict__ out,
                           float* __restrict__ partial)
{
    // per-wave private 64-row slices, packed 25-float rows
    __shared__ __align__(16) float lds[4][1600];
    __shared__ float wsum[4];

    const int tid  = threadIdx.x;
    const int wid  = tid >> 6;
    const int lane = tid & 63;
    // bijective XCD swizzle: 16384 blocks, 8 XCDs, 2048 contiguous per XCD
    const int bid = (blockIdx.x & 7) * 2048 + (blockIdx.x >> 3);
    const int i = bid * 256 + tid;

    const float x = __builtin_nontemporal_load(&x_in[i]);

    // ---- reg-stage this wave's 64 rows: 400 float4, 7 coalesced loads ----
    const float4* ps = (const float4*)params + (size_t)bid * 1600 + wid * 400;
    float4 r0 = ps[lane];
    float4 r1 = ps[lane + 64];
    float4 r2 = ps[lane + 128];
    float4 r3 = ps[lane + 192];
    float4 r4 = ps[lane + 256];
    float4 r5 = ps[lane + 320];
    float4 r6;
    if (lane < 16) r6 = ps[384 + lane];

    float4* bd = (float4*)&lds[wid][0];
    bd[lane]       = r0;
    bd[lane + 64]  = r1;
    bd[lane + 128] = r2;
    bd[lane + 192] = r3;
    bd[lane + 256] = r4;
    bd[lane + 320] = r5;
    if (lane < 16) bd[384 + lane] = r6;

    // wave-private slice; DS ops from one wave complete in order, but fence
    // the cross-lane write->read dependency explicitly.
    asm volatile("s_waitcnt lgkmcnt(0)" ::: "memory");

    const float* row = &lds[wid][lane * 25];
    const float xi = fminf(fmaxf(x, -TAILB), TAILB);
    const float fac_num = (2.0f * TAILB) * (2.0f * TAILB - 8.0f * MINSZ); // 35.952

    // ---- widths: softmax (no max-sub; N(0,1) inputs, fp32-safe) ----
    float ew[8];
    float s = 0.0f;
    #pragma unroll
    for (int j = 0; j < 8; ++j) { ew[j] = __expf(row[j]); s += ew[j]; }
    const float facw = fac_num * frcp(s);

    // fused cumsum + count + knot select (inner knots are monotone)
    float c = 0.0f;
    int idx = 0;
    float cw_k = -TAILB, cw_k1 = TAILB;
    bool found = false;
    #pragma unroll
    for (int j = 0; j < 7; ++j) {
        c = fmaf(ew[j], facw, c + MINSZ);
        const bool ge = (xi >= c);
        idx += ge ? 1 : 0;
        cw_k  = ge ? c : cw_k;
        cw_k1 = (!ge && !found) ? c : cw_k1;
        found = found || !ge;
    }

    // ---- heights: softmax + select by idx ----
    float ch_k = -TAILB, ch_k1 = TAILB;
    {
        float eh[8];
        float sh = 0.0f;
        #pragma unroll
        for (int j = 0; j < 8; ++j) { eh[j] = __expf(row[8 + j]); sh += eh[j]; }
        const float fach = fac_num * frcp(sh);
        c = 0.0f;
        #pragma unroll
        for (int j = 1; j <= 7; ++j) {
            c = fmaf(eh[j - 1], fach, c + MINSZ);
            ch_k  = (idx == j)     ? c : ch_k;
            ch_k1 = (idx + 1 == j) ? c : ch_k1;
        }
    }

    // ---- derivatives: exactly the 2 needed (idx==0 makes d_k == d0) ----
    const float d_k  = softplus_d(row[16 + idx]);
    const float d_k1 = softplus_d(row[17 + idx]);

    // ---- rational-quadratic transform ----
    const float bw  = cw_k1 - cw_k;
    const float bh  = ch_k1 - ch_k;
    const float rbw = frcp(bw);
    const float th  = (xi - cw_k) * rbw;
    const float omt = 1.0f - th;
    const float th2 = th * th;
    const float t1m = th * omt;
    const float num = bh * fmaf(d_k, th2, d_k1 * t1m);
    const float den = fmaf(2.0f * d_k1, t1m, fmaf(d_k, th2, omt * omt));
    const float out_in = fmaf(num, frcp(den), ch_k);

    const bool inside = (x >= -TAILB) && (x <= TAILB);
    __builtin_nontemporal_store(inside ? out_in : x, &out[i]);

    // log(dk1*dk*bh/bw); merged with outside branch's log(d0): ONE v_log_f32
    float ldarg = d_k1 * d_k * bh * rbw;
    if (!__all(inside)) {                 // only waves containing a tail lane
        const float d0 = softplus_d(row[16]);
        ldarg = inside ? ldarg : d0;
    }
    const float ldv = __logf(ldarg);

    // ---- wave reduce; single block combine (the only sync point) ----
    float acc = ldv;
    #pragma unroll
    for (int off = 32; off > 0; off >>= 1)
        acc += __shfl_down(acc, off);
    if (lane == 0) wsum[wid] = acc;
    __syncthreads();
    if (tid == 0)
        __builtin_nontemporal_store((wsum[0] + wsum[1]) + (wsum[2] + wsum[3]),
                                    &partial[bid]);
}

__global__ void rqs_reduce(const float* __restrict__ partial, int nb,
                           float* __restrict__ out_sum)
{
    const int tid = threadIdx.x;              // 1024 threads
    const int nb4 = nb >> 2;                  // nb divisible by 4
    const float4* p4 = (const float4*)partial;
    double acc = 0.0;
    for (int q = tid; q < nb4; q += 1024) {
        float4 v = p4[q];
        acc += (double)v.x + (double)v.y + (double)v.z + (double)v.w;
    }
    #pragma unroll
    for (int off = 32; off > 0; off >>= 1)
        acc += __shfl_down(acc, off);
    __shared__ double wsum[16];
    const int wave = tid >> 6, lane = tid & 63;
    if (lane == 0) wsum[wave] = acc;
    __syncthreads();
    if (tid == 0) {
        double t = 0.0;
        #pragma unroll
        for (int w = 0; w < 16; ++w) t += wsum[w];
        *out_sum = (float)t;
    }
}

extern "C" void kernel_launch(void* const* d_in, const int* in_sizes, int n_in,
                              void* d_out, int out_size, void* d_ws, size_t ws_size,
                              hipStream_t stream) {
    const float* x      = (const float*)d_in[0];
    const float* params = (const float*)d_in[1];
    float* out = (float*)d_out;
    const int n = in_sizes[0];          // 4194304, divisible by 256
    const int nb = n / 256;             // 16384 blocks (divisible by 8)
    float* partial = (float*)d_ws;      // nb*4 = 64 KB scratch

    hipLaunchKernelGGL(rqs_kernel, dim3(nb), dim3(256), 0, stream,
                       x, params, out, partial);
    hipLaunchKernelGGL(rqs_reduce, dim3(1), dim3(1024), 0, stream,
                       partial, nb, out + n);
}